// Round 1
// baseline (513.484 us; speedup 1.0000x reference)
//
#include <hip/hip_runtime.h>

// Aggregator: scores = mean(ue*nr, dim) ; softmax over 32 neighbors ;
// out = relu(mean(w * nv, neighbors)).  One wave (64 lanes) per (b, iter).
// B=4096, NITER=8, NSIZE=32, DIM=64 (derived/fixed for this problem).

constexpr int DIM = 64;
constexpr int NSIZE = 32;

__global__ __launch_bounds__(256) void Aggregator_kernel(
    const float* __restrict__ nv,   // [B, NITER*NSIZE, DIM]
    const float* __restrict__ nr,   // [B, NITER*NSIZE, DIM]
    const float* __restrict__ ue,   // [B, DIM]
    float* __restrict__ out,        // [B, NITER, DIM]
    int niter, int ntasks) {
  int wave = (int)((blockIdx.x * blockDim.x + threadIdx.x) >> 6);
  if (wave >= ntasks) return;
  int lane = (int)(threadIdx.x & 63);
  int b = wave / niter;  // niter=8; compiler emits magic-mul

  const float* nr_base = nr + (size_t)wave * (NSIZE * DIM);
  const float* nv_base = nv + (size_t)wave * (NSIZE * DIM);
  const float* ue_base = ue + (size_t)b * DIM;

  // ---- score stage: lane = (s, half). Each lane: 32-wide half dot product.
  int h = lane >> 5;   // which half of dim
  int s = lane & 31;   // neighbor index

  const float4* nr4 = (const float4*)(nr_base + s * DIM + h * 32);
  const float4* ue4 = (const float4*)(ue_base + h * 32);
  float p = 0.f;
#pragma unroll
  for (int j = 0; j < 8; ++j) {
    float4 a = nr4[j];
    float4 u = ue4[j];
    p = fmaf(a.x, u.x, p);
    p = fmaf(a.y, u.y, p);
    p = fmaf(a.z, u.z, p);
    p = fmaf(a.w, u.w, p);
  }
  p += __shfl_xor(p, 32);          // combine the two halves -> full 64-dot
  float sc = p * (1.0f / DIM);     // mean over dim

  // ---- softmax over the 32 neighbors (lanes 0..31 and 32..63 hold
  // identical copies, so a 32-wide butterfly is consistent in both halves).
  float m = sc;
#pragma unroll
  for (int k = 1; k < 32; k <<= 1) m = fmaxf(m, __shfl_xor(m, k));
  float e = __expf(sc - m);
  float sum = e;
#pragma unroll
  for (int k = 1; k < 32; k <<= 1) sum += __shfl_xor(sum, k);
  float w = e / (sum * (float)NSIZE);   // fold the 1/NSIZE neighbor-mean in

  // ---- output stage: lane = d. Broadcast w_s via readlane (SGPR),
  // coalesced nv loads (64 lanes x 4B contiguous per s).
  float acc = 0.f;
#pragma unroll
  for (int si = 0; si < NSIZE; ++si) {
    float ws = __int_as_float(__builtin_amdgcn_readlane(__float_as_int(w), si));
    acc = fmaf(ws, nv_base[si * DIM + lane], acc);
  }
  out[(size_t)wave * DIM + lane] = fmaxf(acc, 0.f);
}

extern "C" void kernel_launch(void* const* d_in, const int* in_sizes, int n_in,
                              void* d_out, int out_size, void* d_ws, size_t ws_size,
                              hipStream_t stream) {
  // inputs: 0=self_vectors (unused), 1=neighbor_vectors, 2=neighbor_relations,
  //         3=user_embeddings, 4=neighbor_size (device scalar, derived instead)
  const float* nv = (const float*)d_in[1];
  const float* nr = (const float*)d_in[2];
  const float* ue = (const float*)d_in[3];
  float* out = (float*)d_out;

  int ntasks = in_sizes[0] / DIM;        // B * NITER
  int niter  = in_sizes[0] / in_sizes[3]; // NITER
  int blocks = (ntasks + 3) / 4;          // 4 waves per 256-thread block
  Aggregator_kernel<<<blocks, 256, 0, stream>>>(nv, nr, ue, out, niter, ntasks);
}